// Round 15
// baseline (1798.283 us; speedup 1.0000x reference)
//
#include <hip/hip_runtime.h>

#define NB 4
#define NN 16384
#define NPT 1024
#define NS 32
#define CIN 64
#define C0 67

typedef float v2f __attribute__((ext_vector_type(2)));

// DPP wave64 reduce ladders (VALU-only; HW-verified correct in rounds 3/5/6/9/10/11/12/14)
#define DPP_MAXF(r, ctrl)                                                                   \
  {                                                                                         \
    unsigned _m = (unsigned)__builtin_amdgcn_update_dpp(                                    \
        (int)__float_as_uint(r), (int)__float_as_uint(r), ctrl, 0xf, 0xf, false);           \
    r = fmaxf(r, __uint_as_float(_m));                                                      \
  }
#define DPP_MINU(r, ctrl)                                                                   \
  {                                                                                         \
    unsigned _m = (unsigned)__builtin_amdgcn_update_dpp((int)(r), (int)(r), ctrl, 0xf, 0xf, \
                                                        false);                             \
    r = (r < _m) ? r : _m;                                                                  \
  }

// ---------------- FPS: one block per batch, 512 threads, 32 pts/thread ----------------
// Round-12/14 proven version (1532-1538us), byte-identical. Structure space exhausted
// across 7 probes (see round-9 comment history); do not churn.
extern "C" __global__ __attribute__((amdgpu_waves_per_eu(2, 2))) __launch_bounds__(512)
void fps_kernel(const float* __restrict__ xyz, float* __restrict__ newxyz) {
  const int b = blockIdx.x;
  const int tid = threadIdx.x;          // 0..511
  const int wv = tid >> 6, lane = tid & 63;
  const float* base = xyz + (size_t)b * (NN * 3);
  __shared__ unsigned long long part[2][8];  // parity-double-buffered wave-winner keys
  __shared__ float sonew[NPT * 3];           // centroid accumulator (12 KB)
  v2f x2[16], y2[16], z2[16], m2[16];
#pragma unroll
  for (int k = 0; k < 32; ++k) {
    int j = (k << 9) + tid;            // same global index mapping as rounds 0-14
    x2[k >> 1][k & 1] = base[3 * j + 0];
    y2[k >> 1][k & 1] = base[3 * j + 1];
    z2[k >> 1][k & 1] = base[3 * j + 2];
    m2[k >> 1][k & 1] = 1e10f;
  }
  // iteration 0: centroid = point 0 (broadcast load)
  float cx = base[0], cy = base[1], cz = base[2];
  if (tid == 0) { sonew[0] = cx; sonew[1] = cy; sonew[2] = cz; }
  v2f cx2 = {cx, cx}, cy2 = {cy, cy}, cz2 = {cz, cz};
  for (int it = 1; it < NPT; ++it) {
    const int p = it & 1;
    float bv = -1.0f;
    {
#pragma clang fp contract(off)
#pragma unroll
      for (int q = 0; q < 16; ++q) {
        v2f dx = x2[q] - cx2;          // exact IEEE sub per half
        v2f dy = y2[q] - cy2;
        v2f dz = z2[q] - cz2;
        v2f qx = dx * dx;              // no contraction (pragma)
        v2f qy = dy * dy;
        v2f qz = dz * dz;
        v2f ss = qx + qy;              // (dx2+dy2)
        v2f dd = ss + qz;              // +dz2   -- reference's exact order
        float a = fminf(m2[q].x, dd.x);
        float bmn = fminf(m2[q].y, dd.y);
        m2[q].x = a;
        m2[q].y = bmn;
        bv = fmaxf(bv, fmaxf(a, bmn)); // fuses to v_max3_f32
      }
    }
    // post-scan: smallest k with md[k]==bv (descending overwrite keeps smallest)
    int bk = 0;
#pragma unroll
    for (int k = 31; k >= 0; --k) {
      float v = (k & 1) ? m2[k >> 1].y : m2[k >> 1].x;
      bk = (v == bv) ? k : bk;
    }
    int bestj = (bk << 9) + tid;
    // phase A: wave max of bv via DPP ladder -> lane 63
    float r = bv;
    DPP_MAXF(r, 0x111); DPP_MAXF(r, 0x112); DPP_MAXF(r, 0x114);
    DPP_MAXF(r, 0x118); DPP_MAXF(r, 0x142); DPP_MAXF(r, 0x143);
    float wmax = __uint_as_float((unsigned)__builtin_amdgcn_readlane((int)__float_as_uint(r), 63));
    // phase B: min index among lanes holding the max (exact equality: min/max return operands)
    unsigned cj = (bv == wmax) ? (unsigned)bestj : 0x7FFFFFFFu;
    DPP_MINU(cj, 0x111); DPP_MINU(cj, 0x112); DPP_MINU(cj, 0x114);
    DPP_MINU(cj, 0x118); DPP_MINU(cj, 0x142); DPP_MINU(cj, 0x143);
    unsigned jw = (unsigned)__builtin_amdgcn_readlane((int)cj, 63);
    if (lane == 0)
      part[p][wv] = ((unsigned long long)__float_as_uint(wmax) << 32) | (unsigned)(~jw);
    __syncthreads();
    // every thread merges the 8 wave winners (broadcast LDS reads); ~j orders ties to min j
    unsigned long long g = part[p][0];
#pragma unroll
    for (int w = 1; w < 8; ++w) {
      unsigned long long o = part[p][w];
      g = (o > g) ? o : g;
    }
    int j = (int)(~(unsigned)g);
    int js = __builtin_amdgcn_readfirstlane(j);      // uniform -> scalar loads
    const float* pc = base + 3 * js;
    cx = pc[0]; cy = pc[1]; cz = pc[2];              // bit-identical to source coords
    if (tid == 0) { float* o3 = sonew + 3 * it; o3[0] = cx; o3[1] = cy; o3[2] = cz; }
    cx2.x = cx; cx2.y = cx;
    cy2.x = cy; cy2.y = cy;
    cz2.x = cz; cz2.y = cz;
    // no second barrier: next iteration writes the OTHER parity's part[] cells
  }
  __syncthreads();
  // one coalesced copy of all 1024 centroids (3072 floats) to global
  float* onew = newxyz + (size_t)b * (NPT * 3);
  for (int i = tid; i < NPT * 3; i += 512) onew[i] = sonew[i];
}

// ------- Fused ball query (blocks 0..1023) + feature transpose (blocks 1024..2047) -------
// Round-12/14 proven, byte-identical.
extern "C" __global__ __launch_bounds__(256)
void ball_kernel(const float* __restrict__ xyz, const float* __restrict__ newxyz,
                 int* __restrict__ ballidx,
                 const float* __restrict__ feats, float* __restrict__ featsT) {
  __shared__ int list[4][NS];
  __shared__ float t[64][65];           // transpose tile (+1 pad: conflict-free both phases)
  if (blockIdx.x >= NB * NPT / 4) {
    // ---------------- transpose role: (B,C,N) -> (B,N,C), 64x64 tile ----------------
    const int tt = blockIdx.x - NB * NPT / 4;
    const int tile = tt & 255, b = tt >> 8;
    const int j0 = tile * 64;
    const int lj = threadIdx.x & 63;    // lane = j (read) / cc (write)
    const int r0 = threadIdx.x >> 6;    // 0..3
    const float* fb = feats + (size_t)b * (CIN * NN);
#pragma unroll
    for (int cc = r0; cc < 64; cc += 4)
      t[cc][lj] = fb[(size_t)cc * NN + j0 + lj];      // coalesced along j
    __syncthreads();
    float* ob = featsT + (size_t)b * (NN * CIN);
#pragma unroll
    for (int jr = r0; jr < 64; jr += 4)
      ob[(size_t)(j0 + jr) * 64 + lj] = t[lj][jr];    // coalesced along cc
    return;
  }
  // ---------------- ball role: one wave per centroid, ordered append, early exit -------
  const int lwv = threadIdx.x >> 6, lane = threadIdx.x & 63;
  const int wid = blockIdx.x * 4 + lwv;  // centroid id, 0..4095
  const int b = wid >> 10;
  const float* base = xyz + (size_t)b * (NN * 3);
  const float* c = newxyz + (size_t)wid * 3;
  float cx = c[0], cy = c[1], cz = c[2];
  float c2 = __fadd_rn(__fadd_rn(__fmul_rn(cx, cx), __fmul_rn(cy, cy)), __fmul_rn(cz, cz));
  int cnt = 0;
  for (int j0 = 0; j0 < NN; j0 += 64) {
    int j = j0 + lane;
    float xx = base[3 * j + 0], xy = base[3 * j + 1], xz = base[3 * j + 2];
    float x2 = __fadd_rn(__fadd_rn(__fmul_rn(xx, xx), __fmul_rn(xy, xy)), __fmul_rn(xz, xz));
    float dt = __fadd_rn(__fadd_rn(__fmul_rn(cx, xx), __fmul_rn(cy, xy)), __fmul_rn(cz, xz));
    float d2 = __fsub_rn(__fadd_rn(c2, x2), __fmul_rn(2.0f, dt));  // (c2+x2) - 2*dot
    bool in = d2 < 0.25f;
    unsigned long long msk = __ballot(in);
    if (in) {
      int pos = cnt + (int)__popcll(msk & ((1ull << lane) - 1ull));
      if (pos < NS) list[lwv][pos] = j;
    }
    cnt += (int)__popcll(msk);
    if (cnt >= NS) break;
  }
  if (lane < NS) {
    int v;
    if (cnt == 0) v = 0;
    else v = (lane < cnt) ? list[lwv][lane] : list[lwv][0];
    ballidx[wid * NS + lane] = v;
  }
}

// ---------------- Gather + MLP(67->64->64->128) + max-pool, one block per (b,m) ----------------
// Round-15 changes (both value-preserving):
//  1. wbuf stride 68->69: stride-68 reads gave bank (4o+c)%32 -> lanes o,o+8,o+16,o+24
//     collide = 8-way conflict on EVERY weight read (ate most of round-14's staging win).
//     Stride 69 -> bank (5o+c)%32, gcd(5,32)=1 -> 2 lanes/bank (o,o+32) = free (m136).
//  2. Layer-3 W3 rows loaded via explicit float4 (rows are 256B, 16B-aligned): 16 load
//     instructions instead of 64 -> 4x fewer TA line-gather transactions. No LDS cost.
extern "C" __global__ __launch_bounds__(256)
void mlp_kernel(const float* __restrict__ xyz, const float* __restrict__ feats,
                const float* __restrict__ featsT,   // point-major copy, or null (fallback)
                const float* __restrict__ newxyz, const int* __restrict__ ballidx,
                const float* __restrict__ W1, const float* __restrict__ b1,
                const float* __restrict__ W2, const float* __restrict__ b2,
                const float* __restrict__ W3, const float* __restrict__ b3,
                float* __restrict__ outf) {
  const int bm = blockIdx.x;
  const int b = bm >> 10, m = bm & 1023;
  const int tid = threadIdx.x;
  __align__(16) __shared__ float bufA[32 * 68];  // h0 (stride 68), then h2 (stride 64)
  __align__(16) __shared__ float bufB[32 * 64];  // h1, then partial max
  __align__(16) __shared__ float wbuf[64 * 69];  // staged W1, then W2 (stride 69: bank-free)
  __shared__ int sidx[NS];
  if (tid < NS) sidx[tid] = ballidx[bm * NS + tid];
  const float* cb = newxyz + (size_t)bm * 3;
  float cx = cb[0], cy = cb[1], cz = cb[2];
  // stage W1 coalesced: 64 rows x 67 cols -> wbuf stride 69, col 67 zeroed
  for (int idx = tid; idx < 64 * C0; idx += 256) {
    int o = idx / C0, cc = idx - o * C0;
    wbuf[o * 69 + cc] = W1[idx];
  }
  if (tid < 64) wbuf[tid * 69 + 67] = 0.0f;
  __syncthreads();
  // gather: 8 threads per sample
  {
    int s = tid >> 3, q = tid & 7;
    int j = sidx[s];
    float* row = bufA + s * 68;
    if (featsT) {
      const float* fr = featsT + ((size_t)b * NN + j) * 64 + (q << 3);
      float4 a0 = *(const float4*)fr;
      float4 a1 = *(const float4*)(fr + 4);
      float* rp = row + 3 + (q << 3);
      rp[0] = a0.x; rp[1] = a0.y; rp[2] = a0.z; rp[3] = a0.w;
      rp[4] = a1.x; rp[5] = a1.y; rp[6] = a1.z; rp[7] = a1.w;
    } else {
      const float* fb = feats + (size_t)b * (CIN * NN) + j;
#pragma unroll
      for (int u = 0; u < 8; ++u) {
        int cc = (q << 3) + u;
        row[3 + cc] = fb[(size_t)cc * NN];
      }
    }
    if (q == 0) {
      const float* p = xyz + ((size_t)b * NN + j) * 3;
      row[0] = __fsub_rn(p[0], cx);
      row[1] = __fsub_rn(p[1], cy);
      row[2] = __fsub_rn(p[2], cz);
      row[67] = 0.0f;
    }
  }
  __syncthreads();
  // layer 1: 67->64   (thread = (o, 8-sample group)), weights from LDS (stride 69)
  {
    const int o = tid & 63, g = tid >> 6;
    float w[68];
    const float* wr = wbuf + o * 69;
#pragma unroll
    for (int c = 0; c < 68; ++c) w[c] = wr[c];   // w[67] staged as 0; conflict-free banks
    float bias = b1[o];
    float acc[8];
#pragma unroll
    for (int k = 0; k < 8; ++k) acc[k] = bias;
#pragma unroll
    for (int c = 0; c < 68; c += 4) {
#pragma unroll
      for (int k = 0; k < 8; ++k) {
        float4 h = *(const float4*)(bufA + (g * 8 + k) * 68 + c);
        acc[k] = fmaf(w[c], h.x, acc[k]);
        acc[k] = fmaf(w[c + 1], h.y, acc[k]);
        acc[k] = fmaf(w[c + 2], h.z, acc[k]);
        acc[k] = fmaf(w[c + 3], h.w, acc[k]);
      }
    }
#pragma unroll
    for (int k = 0; k < 8; ++k) bufB[(g * 8 + k) * 64 + o] = fmaxf(acc[k], 0.0f);
  }
  __syncthreads();
  // stage W2 (overwrites wbuf; layer-1 reads are done)
  for (int idx = tid; idx < 64 * 64; idx += 256) {
    int o = idx >> 6, cc = idx & 63;
    wbuf[o * 69 + cc] = W2[idx];
  }
  __syncthreads();
  // layer 2: 64->64, h2 into bufA with stride 64, weights from LDS (stride 69)
  {
    const int o = tid & 63, g = tid >> 6;
    float w[64];
    const float* wr = wbuf + o * 69;
#pragma unroll
    for (int c = 0; c < 64; ++c) w[c] = wr[c];
    float bias = b2[o];
    float acc[8];
#pragma unroll
    for (int k = 0; k < 8; ++k) acc[k] = bias;
#pragma unroll
    for (int c = 0; c < 64; c += 4) {
#pragma unroll
      for (int k = 0; k < 8; ++k) {
        float4 h = *(const float4*)(bufB + (g * 8 + k) * 64 + c);
        acc[k] = fmaf(w[c], h.x, acc[k]);
        acc[k] = fmaf(w[c + 1], h.y, acc[k]);
        acc[k] = fmaf(w[c + 2], h.z, acc[k]);
        acc[k] = fmaf(w[c + 3], h.w, acc[k]);
      }
    }
#pragma unroll
    for (int k = 0; k < 8; ++k) bufA[(g * 8 + k) * 64 + o] = fmaxf(acc[k], 0.0f);
  }
  __syncthreads();
  // layer 3: 64->128 (thread = (o128, 16-sample group)), fused relu+max
  // W3 row via float4: 16 load instrs instead of 64 (4x fewer line-gather transactions)
  {
    const int o = tid & 127, g = tid >> 7;
    float w[64];
    const float4* wr4 = (const float4*)(W3 + o * 64);   // 256B rows, 16B-aligned
#pragma unroll
    for (int c4 = 0; c4 < 16; ++c4) {
      float4 v = wr4[c4];
      w[4 * c4 + 0] = v.x; w[4 * c4 + 1] = v.y;
      w[4 * c4 + 2] = v.z; w[4 * c4 + 3] = v.w;
    }
    float bias = b3[o];
    float acc[16];
#pragma unroll
    for (int k = 0; k < 16; ++k) acc[k] = bias;
#pragma unroll
    for (int kb = 0; kb < 16; kb += 8) {   // 8-sample sub-blocks to limit live registers
#pragma unroll
      for (int c = 0; c < 64; c += 4) {
#pragma unroll
        for (int k = 0; k < 8; ++k) {
          float4 h = *(const float4*)(bufA + (g * 16 + kb + k) * 64 + c);
          acc[kb + k] = fmaf(w[c], h.x, acc[kb + k]);
          acc[kb + k] = fmaf(w[c + 1], h.y, acc[kb + k]);
          acc[kb + k] = fmaf(w[c + 2], h.z, acc[kb + k]);
          acc[kb + k] = fmaf(w[c + 3], h.w, acc[kb + k]);
        }
      }
    }
    float mx = 0.0f;
#pragma unroll
    for (int k = 0; k < 16; ++k) mx = fmaxf(mx, fmaxf(acc[k], 0.0f));
    bufB[g * 128 + o] = mx;
  }
  __syncthreads();
  if (tid < 128) {
    float v = fmaxf(bufB[tid], bufB[128 + tid]);
    outf[((size_t)b * 128 + tid) * NPT + m] = v;
  }
}

extern "C" void kernel_launch(void* const* d_in, const int* in_sizes, int n_in,
                              void* d_out, int out_size, void* d_ws, size_t ws_size,
                              hipStream_t stream) {
  const float* xyz   = (const float*)d_in[0];
  const float* feats = (const float*)d_in[1];
  const float* W1 = (const float*)d_in[2];
  const float* b1 = (const float*)d_in[3];
  const float* W2 = (const float*)d_in[4];
  const float* b2 = (const float*)d_in[5];
  const float* W3 = (const float*)d_in[6];
  const float* b3 = (const float*)d_in[7];
  float* out = (float*)d_out;
  float* newxyz = out;                 // (4,1024,3)
  float* outf = out + NB * NPT * 3;    // (4,128,1024)
  int* ballidx = (int*)d_ws;           // 4096*32 ints at ws+0

  // featsT (16.78 MB) lives at ws+1MB if the workspace is big enough; else fall back
  const size_t ftOff = 1u << 20;
  const size_t ftBytes = (size_t)NB * NN * CIN * sizeof(float);
  float* featsT = (ws_size >= ftOff + ftBytes) ? (float*)((char*)d_ws + ftOff) : nullptr;

  hipLaunchKernelGGL(fps_kernel, dim3(NB), dim3(512), 0, stream, xyz, newxyz);
  // ball blocks 0..1023 + transpose blocks 1024..2047 in one dispatch (tr hides in ball)
  const int bgrid = featsT ? (NB * NPT / 4 + NB * (NN / 64)) : (NB * NPT / 4);
  hipLaunchKernelGGL(ball_kernel, dim3(bgrid), dim3(256), 0, stream,
                     xyz, newxyz, ballidx, feats, featsT);
  hipLaunchKernelGGL(mlp_kernel, dim3(NB * NPT), dim3(256), 0, stream,
                     xyz, feats, featsT, newxyz, ballidx, W1, b1, W2, b2, W3, b3, outf);
}

// Round 16
// 1784.772 us; speedup vs baseline: 1.0076x; 1.0076x over previous
//
#include <hip/hip_runtime.h>

#define NB 4
#define NN 16384
#define NPT 1024
#define NS 32
#define CIN 64
#define C0 67

typedef float v2f __attribute__((ext_vector_type(2)));

// DPP wave64 reduce ladders (VALU-only; HW-verified correct in rounds 3/5/6/9/10/11/12/14/15)
#define DPP_MAXF(r, ctrl)                                                                   \
  {                                                                                         \
    unsigned _m = (unsigned)__builtin_amdgcn_update_dpp(                                    \
        (int)__float_as_uint(r), (int)__float_as_uint(r), ctrl, 0xf, 0xf, false);           \
    r = fmaxf(r, __uint_as_float(_m));                                                      \
  }
#define DPP_MINU(r, ctrl)                                                                   \
  {                                                                                         \
    unsigned _m = (unsigned)__builtin_amdgcn_update_dpp((int)(r), (int)(r), ctrl, 0xf, 0xf, \
                                                        false);                             \
    r = (r < _m) ? r : _m;                                                                  \
  }

// ---------------- FPS: one block per batch, 512 threads, 32 pts/thread ----------------
// Round-12/14/15 proven version (1531-1538us), byte-identical. Structure space exhausted
// across 7 probes; do not churn.
extern "C" __global__ __attribute__((amdgpu_waves_per_eu(2, 2))) __launch_bounds__(512)
void fps_kernel(const float* __restrict__ xyz, float* __restrict__ newxyz) {
  const int b = blockIdx.x;
  const int tid = threadIdx.x;          // 0..511
  const int wv = tid >> 6, lane = tid & 63;
  const float* base = xyz + (size_t)b * (NN * 3);
  __shared__ unsigned long long part[2][8];  // parity-double-buffered wave-winner keys
  __shared__ float sonew[NPT * 3];           // centroid accumulator (12 KB)
  v2f x2[16], y2[16], z2[16], m2[16];
#pragma unroll
  for (int k = 0; k < 32; ++k) {
    int j = (k << 9) + tid;            // same global index mapping as rounds 0-15
    x2[k >> 1][k & 1] = base[3 * j + 0];
    y2[k >> 1][k & 1] = base[3 * j + 1];
    z2[k >> 1][k & 1] = base[3 * j + 2];
    m2[k >> 1][k & 1] = 1e10f;
  }
  // iteration 0: centroid = point 0 (broadcast load)
  float cx = base[0], cy = base[1], cz = base[2];
  if (tid == 0) { sonew[0] = cx; sonew[1] = cy; sonew[2] = cz; }
  v2f cx2 = {cx, cx}, cy2 = {cy, cy}, cz2 = {cz, cz};
  for (int it = 1; it < NPT; ++it) {
    const int p = it & 1;
    float bv = -1.0f;
    {
#pragma clang fp contract(off)
#pragma unroll
      for (int q = 0; q < 16; ++q) {
        v2f dx = x2[q] - cx2;          // exact IEEE sub per half
        v2f dy = y2[q] - cy2;
        v2f dz = z2[q] - cz2;
        v2f qx = dx * dx;              // no contraction (pragma)
        v2f qy = dy * dy;
        v2f qz = dz * dz;
        v2f ss = qx + qy;              // (dx2+dy2)
        v2f dd = ss + qz;              // +dz2   -- reference's exact order
        float a = fminf(m2[q].x, dd.x);
        float bmn = fminf(m2[q].y, dd.y);
        m2[q].x = a;
        m2[q].y = bmn;
        bv = fmaxf(bv, fmaxf(a, bmn)); // fuses to v_max3_f32
      }
    }
    // post-scan: smallest k with md[k]==bv (descending overwrite keeps smallest)
    int bk = 0;
#pragma unroll
    for (int k = 31; k >= 0; --k) {
      float v = (k & 1) ? m2[k >> 1].y : m2[k >> 1].x;
      bk = (v == bv) ? k : bk;
    }
    int bestj = (bk << 9) + tid;
    // phase A: wave max of bv via DPP ladder -> lane 63
    float r = bv;
    DPP_MAXF(r, 0x111); DPP_MAXF(r, 0x112); DPP_MAXF(r, 0x114);
    DPP_MAXF(r, 0x118); DPP_MAXF(r, 0x142); DPP_MAXF(r, 0x143);
    float wmax = __uint_as_float((unsigned)__builtin_amdgcn_readlane((int)__float_as_uint(r), 63));
    // phase B: min index among lanes holding the max (exact equality: min/max return operands)
    unsigned cj = (bv == wmax) ? (unsigned)bestj : 0x7FFFFFFFu;
    DPP_MINU(cj, 0x111); DPP_MINU(cj, 0x112); DPP_MINU(cj, 0x114);
    DPP_MINU(cj, 0x118); DPP_MINU(cj, 0x142); DPP_MINU(cj, 0x143);
    unsigned jw = (unsigned)__builtin_amdgcn_readlane((int)cj, 63);
    if (lane == 0)
      part[p][wv] = ((unsigned long long)__float_as_uint(wmax) << 32) | (unsigned)(~jw);
    __syncthreads();
    // every thread merges the 8 wave winners (broadcast LDS reads); ~j orders ties to min j
    unsigned long long g = part[p][0];
#pragma unroll
    for (int w = 1; w < 8; ++w) {
      unsigned long long o = part[p][w];
      g = (o > g) ? o : g;
    }
    int j = (int)(~(unsigned)g);
    int js = __builtin_amdgcn_readfirstlane(j);      // uniform -> scalar loads
    const float* pc = base + 3 * js;
    cx = pc[0]; cy = pc[1]; cz = pc[2];              // bit-identical to source coords
    if (tid == 0) { float* o3 = sonew + 3 * it; o3[0] = cx; o3[1] = cy; o3[2] = cz; }
    cx2.x = cx; cx2.y = cx;
    cy2.x = cy; cy2.y = cy;
    cz2.x = cz; cz2.y = cz;
    // no second barrier: next iteration writes the OTHER parity's part[] cells
  }
  __syncthreads();
  // one coalesced copy of all 1024 centroids (3072 floats) to global
  float* onew = newxyz + (size_t)b * (NPT * 3);
  for (int i = tid; i < NPT * 3; i += 512) onew[i] = sonew[i];
}

// ------- Fused ball query (blocks 0..1023) + feature transpose (blocks 1024..2047) -------
// Round-12/14 proven, byte-identical.
extern "C" __global__ __launch_bounds__(256)
void ball_kernel(const float* __restrict__ xyz, const float* __restrict__ newxyz,
                 int* __restrict__ ballidx,
                 const float* __restrict__ feats, float* __restrict__ featsT) {
  __shared__ int list[4][NS];
  __shared__ float t[64][65];           // transpose tile (+1 pad: conflict-free both phases)
  if (blockIdx.x >= NB * NPT / 4) {
    // ---------------- transpose role: (B,C,N) -> (B,N,C), 64x64 tile ----------------
    const int tt = blockIdx.x - NB * NPT / 4;
    const int tile = tt & 255, b = tt >> 8;
    const int j0 = tile * 64;
    const int lj = threadIdx.x & 63;    // lane = j (read) / cc (write)
    const int r0 = threadIdx.x >> 6;    // 0..3
    const float* fb = feats + (size_t)b * (CIN * NN);
#pragma unroll
    for (int cc = r0; cc < 64; cc += 4)
      t[cc][lj] = fb[(size_t)cc * NN + j0 + lj];      // coalesced along j
    __syncthreads();
    float* ob = featsT + (size_t)b * (NN * CIN);
#pragma unroll
    for (int jr = r0; jr < 64; jr += 4)
      ob[(size_t)(j0 + jr) * 64 + lj] = t[lj][jr];    // coalesced along cc
    return;
  }
  // ---------------- ball role: one wave per centroid, ordered append, early exit -------
  const int lwv = threadIdx.x >> 6, lane = threadIdx.x & 63;
  const int wid = blockIdx.x * 4 + lwv;  // centroid id, 0..4095
  const int b = wid >> 10;
  const float* base = xyz + (size_t)b * (NN * 3);
  const float* c = newxyz + (size_t)wid * 3;
  float cx = c[0], cy = c[1], cz = c[2];
  float c2 = __fadd_rn(__fadd_rn(__fmul_rn(cx, cx), __fmul_rn(cy, cy)), __fmul_rn(cz, cz));
  int cnt = 0;
  for (int j0 = 0; j0 < NN; j0 += 64) {
    int j = j0 + lane;
    float xx = base[3 * j + 0], xy = base[3 * j + 1], xz = base[3 * j + 2];
    float x2 = __fadd_rn(__fadd_rn(__fmul_rn(xx, xx), __fmul_rn(xy, xy)), __fmul_rn(xz, xz));
    float dt = __fadd_rn(__fadd_rn(__fmul_rn(cx, xx), __fmul_rn(cy, xy)), __fmul_rn(cz, xz));
    float d2 = __fsub_rn(__fadd_rn(c2, x2), __fmul_rn(2.0f, dt));  // (c2+x2) - 2*dot
    bool in = d2 < 0.25f;
    unsigned long long msk = __ballot(in);
    if (in) {
      int pos = cnt + (int)__popcll(msk & ((1ull << lane) - 1ull));
      if (pos < NS) list[lwv][pos] = j;
    }
    cnt += (int)__popcll(msk);
    if (cnt >= NS) break;
  }
  if (lane < NS) {
    int v;
    if (cnt == 0) v = 0;
    else v = (lane < cnt) ? list[lwv][lane] : list[lwv][0];
    ballidx[wid * NS + lane] = v;
  }
}

// ---------------- Gather + MLP(67->64->64->128) + max-pool, one block per (b,m) ----------------
// Round-16 isolation: wbuf back to STRIDE 68 (round-14 proven best -- stride 69 broke the
// rows' 16B alignment, degrading ds_read_b128 to 68 scalar ds_read_b32; the 8-way-
// conflicted b128s were still cheaper). ONLY surviving round-15 change: layer-3 W3 rows
// loaded via explicit float4 (256B rows are 16B-aligned) -- 16 load instrs instead of 64,
// 4x fewer TA line-gather transactions, no alignment/LDS cost.
extern "C" __global__ __launch_bounds__(256)
void mlp_kernel(const float* __restrict__ xyz, const float* __restrict__ feats,
                const float* __restrict__ featsT,   // point-major copy, or null (fallback)
                const float* __restrict__ newxyz, const int* __restrict__ ballidx,
                const float* __restrict__ W1, const float* __restrict__ b1,
                const float* __restrict__ W2, const float* __restrict__ b2,
                const float* __restrict__ W3, const float* __restrict__ b3,
                float* __restrict__ outf) {
  const int bm = blockIdx.x;
  const int b = bm >> 10, m = bm & 1023;
  const int tid = threadIdx.x;
  __align__(16) __shared__ float bufA[32 * 68];  // h0 (stride 68), then h2 (stride 64)
  __align__(16) __shared__ float bufB[32 * 64];  // h1, then partial max
  __align__(16) __shared__ float wbuf[64 * 68];  // staged W1, then W2 (stride 68, 16B-aligned)
  __shared__ int sidx[NS];
  if (tid < NS) sidx[tid] = ballidx[bm * NS + tid];
  const float* cb = newxyz + (size_t)bm * 3;
  float cx = cb[0], cy = cb[1], cz = cb[2];
  // stage W1 coalesced: 64 rows x 67 cols -> wbuf stride 68, col 67 zeroed
  for (int idx = tid; idx < 64 * C0; idx += 256) {
    int o = idx / C0, cc = idx - o * C0;
    wbuf[o * 68 + cc] = W1[idx];
  }
  if (tid < 64) wbuf[tid * 68 + 67] = 0.0f;
  __syncthreads();
  // gather: 8 threads per sample
  {
    int s = tid >> 3, q = tid & 7;
    int j = sidx[s];
    float* row = bufA + s * 68;
    if (featsT) {
      const float* fr = featsT + ((size_t)b * NN + j) * 64 + (q << 3);
      float4 a0 = *(const float4*)fr;
      float4 a1 = *(const float4*)(fr + 4);
      float* rp = row + 3 + (q << 3);
      rp[0] = a0.x; rp[1] = a0.y; rp[2] = a0.z; rp[3] = a0.w;
      rp[4] = a1.x; rp[5] = a1.y; rp[6] = a1.z; rp[7] = a1.w;
    } else {
      const float* fb = feats + (size_t)b * (CIN * NN) + j;
#pragma unroll
      for (int u = 0; u < 8; ++u) {
        int cc = (q << 3) + u;
        row[3 + cc] = fb[(size_t)cc * NN];
      }
    }
    if (q == 0) {
      const float* p = xyz + ((size_t)b * NN + j) * 3;
      row[0] = __fsub_rn(p[0], cx);
      row[1] = __fsub_rn(p[1], cy);
      row[2] = __fsub_rn(p[2], cz);
      row[67] = 0.0f;
    }
  }
  __syncthreads();
  // layer 1: 67->64   (thread = (o, 8-sample group)), weights from LDS
  {
    const int o = tid & 63, g = tid >> 6;
    float w[68];
    const float* wr = wbuf + o * 68;     // 272B rows, 16B-aligned -> ds_read_b128
#pragma unroll
    for (int c = 0; c < 68; ++c) w[c] = wr[c];   // w[67] staged as 0
    float bias = b1[o];
    float acc[8];
#pragma unroll
    for (int k = 0; k < 8; ++k) acc[k] = bias;
#pragma unroll
    for (int c = 0; c < 68; c += 4) {
#pragma unroll
      for (int k = 0; k < 8; ++k) {
        float4 h = *(const float4*)(bufA + (g * 8 + k) * 68 + c);
        acc[k] = fmaf(w[c], h.x, acc[k]);
        acc[k] = fmaf(w[c + 1], h.y, acc[k]);
        acc[k] = fmaf(w[c + 2], h.z, acc[k]);
        acc[k] = fmaf(w[c + 3], h.w, acc[k]);
      }
    }
#pragma unroll
    for (int k = 0; k < 8; ++k) bufB[(g * 8 + k) * 64 + o] = fmaxf(acc[k], 0.0f);
  }
  __syncthreads();
  // stage W2 (overwrites wbuf; layer-1 reads are done)
  for (int idx = tid; idx < 64 * 64; idx += 256) {
    int o = idx >> 6, cc = idx & 63;
    wbuf[o * 68 + cc] = W2[idx];
  }
  __syncthreads();
  // layer 2: 64->64, h2 into bufA with stride 64, weights from LDS
  {
    const int o = tid & 63, g = tid >> 6;
    float w[64];
    const float* wr = wbuf + o * 68;
#pragma unroll
    for (int c = 0; c < 64; ++c) w[c] = wr[c];
    float bias = b2[o];
    float acc[8];
#pragma unroll
    for (int k = 0; k < 8; ++k) acc[k] = bias;
#pragma unroll
    for (int c = 0; c < 64; c += 4) {
#pragma unroll
      for (int k = 0; k < 8; ++k) {
        float4 h = *(const float4*)(bufB + (g * 8 + k) * 64 + c);
        acc[k] = fmaf(w[c], h.x, acc[k]);
        acc[k] = fmaf(w[c + 1], h.y, acc[k]);
        acc[k] = fmaf(w[c + 2], h.z, acc[k]);
        acc[k] = fmaf(w[c + 3], h.w, acc[k]);
      }
    }
#pragma unroll
    for (int k = 0; k < 8; ++k) bufA[(g * 8 + k) * 64 + o] = fmaxf(acc[k], 0.0f);
  }
  __syncthreads();
  // layer 3: 64->128 (thread = (o128, 16-sample group)), fused relu+max
  // W3 row via float4: 16 load instrs instead of 64 (4x fewer line-gather transactions)
  {
    const int o = tid & 127, g = tid >> 7;
    float w[64];
    const float4* wr4 = (const float4*)(W3 + o * 64);   // 256B rows, 16B-aligned
#pragma unroll
    for (int c4 = 0; c4 < 16; ++c4) {
      float4 v = wr4[c4];
      w[4 * c4 + 0] = v.x; w[4 * c4 + 1] = v.y;
      w[4 * c4 + 2] = v.z; w[4 * c4 + 3] = v.w;
    }
    float bias = b3[o];
    float acc[16];
#pragma unroll
    for (int k = 0; k < 16; ++k) acc[k] = bias;
#pragma unroll
    for (int kb = 0; kb < 16; kb += 8) {   // 8-sample sub-blocks to limit live registers
#pragma unroll
      for (int c = 0; c < 64; c += 4) {
#pragma unroll
        for (int k = 0; k < 8; ++k) {
          float4 h = *(const float4*)(bufA + (g * 16 + kb + k) * 64 + c);
          acc[kb + k] = fmaf(w[c], h.x, acc[kb + k]);
          acc[kb + k] = fmaf(w[c + 1], h.y, acc[kb + k]);
          acc[kb + k] = fmaf(w[c + 2], h.z, acc[kb + k]);
          acc[kb + k] = fmaf(w[c + 3], h.w, acc[kb + k]);
        }
      }
    }
    float mx = 0.0f;
#pragma unroll
    for (int k = 0; k < 16; ++k) mx = fmaxf(mx, fmaxf(acc[k], 0.0f));
    bufB[g * 128 + o] = mx;
  }
  __syncthreads();
  if (tid < 128) {
    float v = fmaxf(bufB[tid], bufB[128 + tid]);
    outf[((size_t)b * 128 + tid) * NPT + m] = v;
  }
}

extern "C" void kernel_launch(void* const* d_in, const int* in_sizes, int n_in,
                              void* d_out, int out_size, void* d_ws, size_t ws_size,
                              hipStream_t stream) {
  const float* xyz   = (const float*)d_in[0];
  const float* feats = (const float*)d_in[1];
  const float* W1 = (const float*)d_in[2];
  const float* b1 = (const float*)d_in[3];
  const float* W2 = (const float*)d_in[4];
  const float* b2 = (const float*)d_in[5];
  const float* W3 = (const float*)d_in[6];
  const float* b3 = (const float*)d_in[7];
  float* out = (float*)d_out;
  float* newxyz = out;                 // (4,1024,3)
  float* outf = out + NB * NPT * 3;    // (4,128,1024)
  int* ballidx = (int*)d_ws;           // 4096*32 ints at ws+0

  // featsT (16.78 MB) lives at ws+1MB if the workspace is big enough; else fall back
  const size_t ftOff = 1u << 20;
  const size_t ftBytes = (size_t)NB * NN * CIN * sizeof(float);
  float* featsT = (ws_size >= ftOff + ftBytes) ? (float*)((char*)d_ws + ftOff) : nullptr;

  hipLaunchKernelGGL(fps_kernel, dim3(NB), dim3(512), 0, stream, xyz, newxyz);
  // ball blocks 0..1023 + transpose blocks 1024..2047 in one dispatch (tr hides in ball)
  const int bgrid = featsT ? (NB * NPT / 4 + NB * (NN / 64)) : (NB * NPT / 4);
  hipLaunchKernelGGL(ball_kernel, dim3(bgrid), dim3(256), 0, stream,
                     xyz, newxyz, ballidx, feats, featsT);
  hipLaunchKernelGGL(mlp_kernel, dim3(NB * NPT), dim3(256), 0, stream,
                     xyz, feats, featsT, newxyz, ballidx, W1, b1, W2, b2, W3, b3, outf);
}